// Round 6
// baseline (591.600 us; speedup 1.0000x reference)
//
#include <hip/hip_runtime.h>

constexpr int NE = 8192;
constexpr int ED = 256;
constexpr int BS = 32768;
constexpr float DELTA = 4e-4f;   // >> 2*(bf16-MFMA err ~6e-6 + np-grid quantization ~3e-5)

typedef short bf16x8 __attribute__((ext_vector_type(8)));
typedef float f32x4 __attribute__((ext_vector_type(4)));

#define GLOAD_LDS16(g, l) __builtin_amdgcn_global_load_lds( \
    (const __attribute__((address_space(1))) void*)(g),     \
    (__attribute__((address_space(3))) void*)(l), 16, 0, 0)

__device__ __forceinline__ short f2bf(float f) {            // RNE f32 -> bf16
    unsigned u = __float_as_uint(f);
    u = u + 0x7FFFu + ((u >> 16) & 1u);
    return (short)(u >> 16);
}
__device__ __forceinline__ unsigned bf16_rd(float x) {      // round toward -inf -> bf16 bits
    unsigned u = __float_as_uint(x);
    unsigned h = u >> 16;
    if ((u & 0x80000000u) && (u & 0xFFFFu)) ++h;
    return h;
}

// ---------- np-exact pairwise ||row||^2 (verified bit-exact vs np.sum in R2) ----------
__global__ void sq_np_kernel(const float* __restrict__ a, float* __restrict__ out) {
    int gtid = blockIdx.x * blockDim.x + threadIdx.x;
    int wave = gtid >> 6;
    int lane = threadIdx.x & 63;
    int sub  = lane & 7;
    int row  = wave * 8 + (lane >> 3);
    const float* p = a + (size_t)row * ED;
    float b0 = 0.f, b1 = 0.f;
#pragma unroll
    for (int t = 0; t < 16; ++t) { float v = p[8 * t + sub];       b0 = __fadd_rn(b0, __fmul_rn(v, v)); }
#pragma unroll
    for (int t = 0; t < 16; ++t) { float v = p[128 + 8 * t + sub]; b1 = __fadd_rn(b1, __fmul_rn(v, v)); }
    b0 = __fadd_rn(b0, __shfl_xor(b0, 1));
    b0 = __fadd_rn(b0, __shfl_xor(b0, 2));
    b0 = __fadd_rn(b0, __shfl_xor(b0, 4));
    b1 = __fadd_rn(b1, __shfl_xor(b1, 1));
    b1 = __fadd_rn(b1, __shfl_xor(b1, 2));
    b1 = __fadd_rn(b1, __shfl_xor(b1, 4));
    if (sub == 0) out[row] = __fadd_rn(b0, b1);
}

// ---------- convert e (f32) -> eb (bf16), row-major, once ----------
__global__ void cvt_bf16_kernel(const float* __restrict__ a, short* __restrict__ o) {
    int i = blockIdx.x * blockDim.x + threadIdx.x;     // one per 8 elements
    const float4* p = reinterpret_cast<const float4*>(a + (size_t)i * 8);
    float4 v0 = p[0], v1 = p[1];
    bf16x8 h;
    h[0] = f2bf(v0.x); h[1] = f2bf(v0.y); h[2] = f2bf(v0.z); h[3] = f2bf(v0.w);
    h[4] = f2bf(v1.x); h[5] = f2bf(v1.y); h[6] = f2bf(v1.z); h[7] = f2bf(v1.w);
    *reinterpret_cast<bf16x8*>(o + (size_t)i * 8) = h;
}

// ---------- pass 1: 64 z-rows per block, loop all 64 col-chunks of 128 ----------
// A (z) converted to bf16 LDS once per block; B staged from eb via global_load_lds
// with pre-swizzled source. Per (row, chunk): {min, argmin, 2nd-min} -> wsp.
__global__ __launch_bounds__(256) void vq_pass1(
        const float* __restrict__ z, const char* __restrict__ ebb,
        const float* __restrict__ e2, uint2* __restrict__ wsp) {
    __shared__ __align__(16) char As[64 * 512];   // 32 KB, row*512 + (ku*16 ^ ((row&7)<<4))
    __shared__ __align__(16) char Bs[128 * 128];  // 16 KB, col*128 + swizzled k-unit
    __shared__ float lm1[2][64], lm2[2][64];
    __shared__ int   lix[2][64];

    const int tid  = threadIdx.x;
    const int row0 = blockIdx.x * 64;
    const int wid  = tid >> 6, lane = tid & 63;
    const int wr   = (wid >> 1) * 32;       // row offset of wave quadrant
    const int wc   = (wid & 1) * 64;        // col offset of wave quadrant
    const int lr   = lane & 15;
    const int lk   = lane >> 4;
    const int sw   = (lr & 7) << 4;

    // ---- stage A: convert z[row0:row0+64, :] to bf16 LDS, swizzled (once) ----
#pragma unroll
    for (int it = 0; it < 8; ++it) {
        int s = tid + it * 256;             // 0..2047 = 64 rows x 32 16B-units
        int r = s >> 5, ku = s & 31;
        const float4* sp = reinterpret_cast<const float4*>(
            z + (size_t)(row0 + r) * ED + ku * 8);
        float4 a0 = sp[0], a1 = sp[1];
        bf16x8 h;
        h[0] = f2bf(a0.x); h[1] = f2bf(a0.y); h[2] = f2bf(a0.z); h[3] = f2bf(a0.w);
        h[4] = f2bf(a1.x); h[5] = f2bf(a1.y); h[6] = f2bf(a1.z); h[7] = f2bf(a1.w);
        *reinterpret_cast<bf16x8*>(As + r * 512 + ((ku * 16) ^ ((r & 7) << 4))) = h;
    }

    // ---- per-lane B staging source offsets (pre-swizzled global address) ----
    size_t bsrc[4];
    char*  bdst[4];
#pragma unroll
    for (int it = 0; it < 4; ++it) {
        int g  = it * 256 + wid * 64 + lane;  // slot 0..1023
        int c  = g >> 3;                      // col 0..127
        int ku = g & 7;                       // 16B k-unit within kstep
        bsrc[it] = (size_t)c * 512 + (size_t)((ku ^ (c & 7)) << 4);
        bdst[it] = Bs + (it * 256 + wid * 64) * 16;   // wave-uniform dest base
    }

    // precompute frag base offsets
    int aoff[2];
#pragma unroll
    for (int i = 0; i < 2; ++i) aoff[i] = (wr + i * 16 + lr) * 512;
    int boff[4];
#pragma unroll
    for (int j = 0; j < 4; ++j) boff[j] = (wc + j * 16 + lr) * 128;

    for (int ch = 0; ch < 64; ++ch) {
        const char* ebB = ebb + (size_t)ch * (128 * 512);
        f32x4 acc[2][4];
#pragma unroll
        for (int i = 0; i < 2; ++i)
#pragma unroll
            for (int j = 0; j < 4; ++j) acc[i][j] = (f32x4){0.f, 0.f, 0.f, 0.f};

        for (int kstep = 0; kstep < 4; ++kstep) {
            __syncthreads();                 // Bs readers / lm-merge done
#pragma unroll
            for (int it = 0; it < 4; ++it)
                GLOAD_LDS16(ebB + bsrc[it] + kstep * 128, bdst[it]);
            asm volatile("s_waitcnt vmcnt(0)" ::: "memory");
            __syncthreads();
#pragma unroll
            for (int ks = 0; ks < 2; ++ks) {
                bf16x8 af[2], bg[4];
#pragma unroll
                for (int i = 0; i < 2; ++i)
                    af[i] = *reinterpret_cast<const bf16x8*>(
                        As + aoff[i] + (((kstep * 8 + ks * 4 + lk) * 16) ^ sw));
#pragma unroll
                for (int j = 0; j < 4; ++j)
                    bg[j] = *reinterpret_cast<const bf16x8*>(
                        Bs + boff[j] + (((ks * 4 + lk) * 16) ^ sw));
#pragma unroll
                for (int i = 0; i < 2; ++i)
#pragma unroll
                    for (int j = 0; j < 4; ++j)
                        acc[i][j] = __builtin_amdgcn_mfma_f32_16x16x32_bf16(
                            af[i], bg[j], acc[i][j], 0, 0, 0);
            }
        }

        // ---- epilogue: per (row, chunk) top-2 of d' = e2 - 2*dot over 128 cols ----
        float e2v[4];
#pragma unroll
        for (int j = 0; j < 4; ++j) e2v[j] = e2[ch * 128 + wc + j * 16 + lr];

#pragma unroll
        for (int i = 0; i < 2; ++i) {
#pragma unroll
            for (int q = 0; q < 4; ++q) {
                float m1 = 3.4e38f, m2 = 3.4e38f;
                int   i1 = 0;
#pragma unroll
                for (int j = 0; j < 4; ++j) {
                    float v = e2v[j] - 2.f * acc[i][j][q];
                    int   c = wc + j * 16 + lr;
                    if (v < m1 || (v == m1 && c < i1)) { m2 = m1; m1 = v; i1 = c; }
                    else m2 = fminf(m2, v);
                }
#pragma unroll
                for (int off = 1; off < 16; off <<= 1) {
                    float om1 = __shfl_xor(m1, off);
                    int   oi1 = __shfl_xor(i1, off);
                    float om2 = __shfl_xor(m2, off);
                    if (om1 < m1 || (om1 == m1 && oi1 < i1)) {
                        m2 = fminf(m1, om2); m1 = om1; i1 = oi1;
                    } else {
                        m2 = fminf(m2, om1);
                    }
                }
                if (lr == 0) {
                    int rloc = wr + i * 16 + lk * 4 + q;   // 0..63
                    lm1[wid & 1][rloc] = m1;
                    lm2[wid & 1][rloc] = m2;
                    lix[wid & 1][rloc] = i1;
                }
            }
        }
        __syncthreads();
        if (tid < 64) {
            float m1a = lm1[0][tid], m2a = lm2[0][tid]; int ia = lix[0][tid];
            float m1b = lm1[1][tid], m2b = lm2[1][tid]; int ib = lix[1][tid];
            float M1, M2; int I1;
            if (m1a < m1b || (m1a == m1b && ia < ib)) { M1 = m1a; I1 = ia; M2 = fminf(m2a, m1b); }
            else                                      { M1 = m1b; I1 = ib; M2 = fminf(m2b, m1a); }
            wsp[(size_t)(row0 + tid) * 64 + ch] =
                make_uint2(__float_as_uint(M1), (bf16_rd(M2) << 16) | (unsigned)I1);
        }
    }
}

// ---------- pass 2: candidate-column exact np re-eval + argmin + gather ----------
__global__ __launch_bounds__(256) void vq_pass2(
        const float* __restrict__ z, const float* __restrict__ e,
        const float* __restrict__ z2, const float* __restrict__ e2,
        const uint2* __restrict__ wsp, float* __restrict__ out) {
    __shared__ __align__(16) float zrow[4][ED];
    const int wid = threadIdx.x >> 6, lane = threadIdx.x & 63;
    const int r = blockIdx.x * 4 + wid;

    *reinterpret_cast<float4*>(&zrow[wid][lane * 4]) =
        *reinterpret_cast<const float4*>(z + (size_t)r * ED + lane * 4);
    __syncthreads();

    const float z2r = z2[r];
    uint2 p = wsp[(size_t)r * 64 + lane];                 // one 128-chunk per lane
    float m1 = __uint_as_float(p.x);
    int   i8 = (int)(p.y & 0xFFu);
    float m2 = __uint_as_float(p.y & 0xFFFF0000u);        // conservative (<= true m2)

    float rmn = m1;
#pragma unroll
    for (int off = 1; off < 64; off <<= 1) rmn = fminf(rmn, __shfl_xor(rmn, off));
    const float thr = rmn + DELTA;

    const bool cF = (m2 <= thr);
    const bool cS = (m1 <= thr) && !cF;
    unsigned long long bS = __ballot(cS);
    unsigned long long bF = __ballot(cF);

    float bd = 3.4e38f;
    int   bc = NE;

    // ---- single-column candidates: batch into lanes, one col per lane ----
    int myCol = -1;
    int cnt = 0;
    unsigned long long m = bS;
    while (true) {
        bool flush = (m == 0) || (cnt == 64);
        if (flush) {
            if (cnt > 0) {
                int ecol = (myCol >= 0) ? myCol : 0;
                const float* ec = e + (size_t)ecol * ED;
                float a0 = 0.f, a1 = 0.f, a2 = 0.f, a3 = 0.f;
#pragma unroll 8
                for (int t = 0; t < 64; ++t) {
                    float4 ev = *reinterpret_cast<const float4*>(ec + 4 * t);
                    float4 zv = *reinterpret_cast<const float4*>(&zrow[wid][4 * t]);
                    a0 = __fadd_rn(a0, __fmul_rn(zv.x, ev.x));
                    a1 = __fadd_rn(a1, __fmul_rn(zv.y, ev.y));
                    a2 = __fadd_rn(a2, __fmul_rn(zv.z, ev.z));
                    a3 = __fadd_rn(a3, __fmul_rn(zv.w, ev.w));
                }
                float s = __fadd_rn(__fadd_rn(a0, a1), __fadd_rn(a2, a3));
                float d = __fsub_rn(__fadd_rn(z2r, e2[ecol]), __fmul_rn(2.0f, s));
                if (myCol >= 0 && (d < bd || (d == bd && ecol < bc))) { bd = d; bc = ecol; }
                myCol = -1; cnt = 0;
            }
            if (m == 0) break;
        }
        int ch = __builtin_ctzll(m); m &= m - 1;
        int col = ch * 128 + __shfl(i8, ch);
        if (lane == cnt) myCol = col;
        ++cnt;
    }

    // ---- full-chunk candidates (rare; covers exact d'-ties automatically) ----
    m = bF;
    while (m) {
        int ch = __builtin_ctzll(m); m &= m - 1;
#pragma unroll
        for (int hh = 0; hh < 2; ++hh) {
            int col = ch * 128 + hh * 64 + lane;
            const float* ec = e + (size_t)col * ED;
            float a0 = 0.f, a1 = 0.f, a2 = 0.f, a3 = 0.f;
#pragma unroll 8
            for (int t = 0; t < 64; ++t) {
                float4 ev = *reinterpret_cast<const float4*>(ec + 4 * t);
                float4 zv = *reinterpret_cast<const float4*>(&zrow[wid][4 * t]);
                a0 = __fadd_rn(a0, __fmul_rn(zv.x, ev.x));
                a1 = __fadd_rn(a1, __fmul_rn(zv.y, ev.y));
                a2 = __fadd_rn(a2, __fmul_rn(zv.z, ev.z));
                a3 = __fadd_rn(a3, __fmul_rn(zv.w, ev.w));
            }
            float s = __fadd_rn(__fadd_rn(a0, a1), __fadd_rn(a2, a3));
            float d = __fsub_rn(__fadd_rn(z2r, e2[col]), __fmul_rn(2.0f, s));
            if (d < bd || (d == bd && col < bc)) { bd = d; bc = col; }
        }
    }

#pragma unroll
    for (int off = 1; off < 64; off <<= 1) {
        float od = __shfl_xor(bd, off);
        int   oc = __shfl_xor(bc, off);
        if (od < bd || (od == bd && oc < bc)) { bd = od; bc = oc; }
    }
    if (lane == 0) out[(size_t)BS * ED + r] = (float)bc;
    *reinterpret_cast<float4*>(out + (size_t)r * ED + lane * 4) =
        *reinterpret_cast<const float4*>(e + (size_t)bc * ED + lane * 4);
}

extern "C" void kernel_launch(void* const* d_in, const int* in_sizes, int n_in,
                              void* d_out, int out_size, void* d_ws, size_t ws_size,
                              hipStream_t stream) {
    const float* z = (const float*)d_in[0];
    const float* e = (const float*)d_in[1];
    float* out   = (float*)d_out;
    float* e2np  = (float*)d_ws;                     // 8192 f32
    float* z2np  = e2np + NE;                        // 32768 f32
    uint2* wsp   = (uint2*)(z2np + BS);              // 32768 x 64 x 8B = 16 MB
    short* eb    = (short*)(wsp + (size_t)BS * 64);  // 8192 x 256 bf16 = 4 MB

    hipLaunchKernelGGL(sq_np_kernel, dim3(NE / 32), dim3(256), 0, stream, e, e2np);
    hipLaunchKernelGGL(sq_np_kernel, dim3(BS / 32), dim3(256), 0, stream, z, z2np);
    hipLaunchKernelGGL(cvt_bf16_kernel, dim3(NE * ED / 8 / 256), dim3(256), 0, stream, e, eb);
    hipLaunchKernelGGL(vq_pass1, dim3(BS / 64), dim3(256), 0, stream,
                       z, (const char*)eb, e2np, wsp);
    hipLaunchKernelGGL(vq_pass2, dim3(BS / 4), dim3(256), 0, stream, z, e, z2np, e2np, wsp, out);
}

// Round 7
// 472.463 us; speedup vs baseline: 1.2522x; 1.2522x over previous
//
#include <hip/hip_runtime.h>

constexpr int NE = 8192;
constexpr int ED = 256;
constexpr int BS = 32768;
constexpr float DELTA = 4e-4f;   // >> 2*(bf16-MFMA err) + np-grid + key-quantization (~7.6e-6)

typedef short bf16x8 __attribute__((ext_vector_type(8)));
typedef float f32x4 __attribute__((ext_vector_type(4)));

#define GLOAD_LDS16(g, l) __builtin_amdgcn_global_load_lds( \
    (const __attribute__((address_space(1))) void*)(g),     \
    (__attribute__((address_space(3))) void*)(l), 16, 0, 0)

__device__ __forceinline__ short f2bf(float f) {            // RNE f32 -> bf16
    unsigned u = __float_as_uint(f);
    u = u + 0x7FFFu + ((u >> 16) & 1u);
    return (short)(u >> 16);
}
__device__ __forceinline__ unsigned bf16_rd(float x) {      // round toward -inf -> bf16 bits
    unsigned u = __float_as_uint(x);
    unsigned h = u >> 16;
    if ((u & 0x80000000u) && (u & 0xFFFFu)) ++h;
    return h;
}
__device__ __forceinline__ unsigned umn(unsigned a, unsigned b) { return a < b ? a : b; }
__device__ __forceinline__ unsigned umx(unsigned a, unsigned b) { return a > b ? a : b; }

// ---------- np-exact pairwise ||row||^2 (verified bit-exact vs np.sum in R2) ----------
__global__ void sq_np_kernel(const float* __restrict__ a, float* __restrict__ out) {
    int gtid = blockIdx.x * blockDim.x + threadIdx.x;
    int wave = gtid >> 6;
    int lane = threadIdx.x & 63;
    int sub  = lane & 7;
    int row  = wave * 8 + (lane >> 3);
    const float* p = a + (size_t)row * ED;
    float b0 = 0.f, b1 = 0.f;
#pragma unroll
    for (int t = 0; t < 16; ++t) { float v = p[8 * t + sub];       b0 = __fadd_rn(b0, __fmul_rn(v, v)); }
#pragma unroll
    for (int t = 0; t < 16; ++t) { float v = p[128 + 8 * t + sub]; b1 = __fadd_rn(b1, __fmul_rn(v, v)); }
    b0 = __fadd_rn(b0, __shfl_xor(b0, 1));
    b0 = __fadd_rn(b0, __shfl_xor(b0, 2));
    b0 = __fadd_rn(b0, __shfl_xor(b0, 4));
    b1 = __fadd_rn(b1, __shfl_xor(b1, 1));
    b1 = __fadd_rn(b1, __shfl_xor(b1, 2));
    b1 = __fadd_rn(b1, __shfl_xor(b1, 4));
    if (sub == 0) out[row] = __fadd_rn(b0, b1);
}

// ---------- convert e (f32) -> eb (bf16), row-major, once ----------
__global__ void cvt_bf16_kernel(const float* __restrict__ a, short* __restrict__ o) {
    int i = blockIdx.x * blockDim.x + threadIdx.x;     // one per 8 elements
    const float4* p = reinterpret_cast<const float4*>(a + (size_t)i * 8);
    float4 v0 = p[0], v1 = p[1];
    bf16x8 h;
    h[0] = f2bf(v0.x); h[1] = f2bf(v0.y); h[2] = f2bf(v0.z); h[3] = f2bf(v0.w);
    h[4] = f2bf(v1.x); h[5] = f2bf(v1.y); h[6] = f2bf(v1.z); h[7] = f2bf(v1.w);
    *reinterpret_cast<bf16x8*>(o + (size_t)i * 8) = h;
}

// ---------- pass 1: A(z) full-K in registers, B(eb) double-buffered LDS ----------
// 8 waves x 64 rows = 512 rows/block; col-quarter of 2048 cols = 32 tiles of 64.
// Per (row, 128-col chunk): u32-key top-2 {m1,i1,m2} -> wsp (pass-2-compatible).
__global__ __launch_bounds__(512, 1) void vq_pass1(
        const float* __restrict__ z, const char* __restrict__ eb,
        const float* __restrict__ e2, uint2* __restrict__ wsp) {
    __shared__ __align__(16) char Bs[2][32768];      // 64 KB double buffer
    __shared__ uint2 top2buf[8][64];                 // per-wave even-tile partials

    const int tid  = threadIdx.x;
    const int wid  = tid >> 6, lane = tid & 63;
    const int l15  = lane & 15, lg = lane >> 4;
    const int brow = (blockIdx.x >> 2) * 512;
    const int q    = blockIdx.x & 3;
    const int c0q  = q * 2048;
    const int wr0  = brow + wid * 64;
    const int swz  = (l15 & 7) << 4;

    // ---- prologue: stage tile 0, then load A frags (64 rows x 256 k, bf16) ----
#pragma unroll
    for (int it = 0; it < 4; ++it) {
        int slot = it * 512 + tid;                   // 0..2047
        int c = slot >> 5, m = slot & 31;
        GLOAD_LDS16(eb + (size_t)(c0q + c) * 512 + ((m ^ (c & 7)) << 4),
                    Bs[0] + slot * 16);
    }
    bf16x8 areg[4][8];
#pragma unroll
    for (int i = 0; i < 4; ++i) {
        const float* zr = z + (size_t)(wr0 + i * 16 + l15) * ED + lg * 8;
#pragma unroll
        for (int t = 0; t < 8; ++t) {
            float4 v0 = *reinterpret_cast<const float4*>(zr + t * 32);
            float4 v1 = *reinterpret_cast<const float4*>(zr + t * 32 + 4);
            bf16x8 h;
            h[0] = f2bf(v0.x); h[1] = f2bf(v0.y); h[2] = f2bf(v0.z); h[3] = f2bf(v0.w);
            h[4] = f2bf(v1.x); h[5] = f2bf(v1.y); h[6] = f2bf(v1.z); h[7] = f2bf(v1.w);
            areg[i][t] = h;
        }
    }

    for (int t = 0; t < 32; ++t) {
        const int buf = t & 1;
        __syncthreads();                 // drains vmcnt(0): tile t staged; prev reads done
        if (t < 31) {                    // issue next tile into other buffer (hidden)
            const char* src = eb + (size_t)(c0q + (t + 1) * 64) * 512;
#pragma unroll
            for (int it = 0; it < 4; ++it) {
                int slot = it * 512 + tid;
                int c = slot >> 5, m = slot & 31;
                GLOAD_LDS16(src + (size_t)c * 512 + ((m ^ (c & 7)) << 4),
                            Bs[buf ^ 1] + slot * 16);
            }
        }
        const int c0 = c0q + t * 64;
        float e2c[4];
#pragma unroll
        for (int j = 0; j < 4; ++j) e2c[j] = e2[c0 + j * 16 + l15] + 0.5f;

        f32x4 acc[4][4];
#pragma unroll
        for (int i = 0; i < 4; ++i)
#pragma unroll
            for (int j = 0; j < 4; ++j) acc[i][j] = (f32x4){0.f, 0.f, 0.f, 0.f};

#pragma unroll
        for (int t8 = 0; t8 < 8; ++t8) {
            bf16x8 bg[4];
#pragma unroll
            for (int j = 0; j < 4; ++j)
                bg[j] = *reinterpret_cast<const bf16x8*>(
                    Bs[buf] + (j * 16 + l15) * 512 + (((t8 * 4 + lg) * 16) ^ swz));
#pragma unroll
            for (int i = 0; i < 4; ++i)
#pragma unroll
                for (int j = 0; j < 4; ++j)
                    acc[i][j] = __builtin_amdgcn_mfma_f32_16x16x32_bf16(
                        areg[i][t8], bg[j], acc[i][j], 0, 0, 0);
        }

        // ---- epilogue: u32-key top-2 per row over this 64-col tile ----
        unsigned colb[4];
#pragma unroll
        for (int j = 0; j < 4; ++j) colb[j] = (unsigned)((t & 1) * 64 + j * 16 + l15);

#pragma unroll
        for (int i = 0; i < 4; ++i) {
#pragma unroll
            for (int qq = 0; qq < 4; ++qq) {
                unsigned kk[4];
#pragma unroll
                for (int j = 0; j < 4; ++j) {
                    float v = fmaf(-2.f, acc[i][j][qq], e2c[j]);   // d' + 0.5 > 0
                    kk[j] = (__float_as_uint(v) & 0xFFFFFF80u) | colb[j];
                }
                unsigned lo1 = umn(kk[0], kk[1]), hi1 = umx(kk[0], kk[1]);
                unsigned lo2 = umn(kk[2], kk[3]), hi2 = umx(kk[2], kk[3]);
                unsigned k1 = umn(lo1, lo2);
                unsigned k2 = umn(umn(hi1, hi2), umx(lo1, lo2));
#pragma unroll
                for (int off = 1; off < 16; off <<= 1) {
                    unsigned o1 = __shfl_xor(k1, off);
                    unsigned o2 = __shfl_xor(k2, off);
                    unsigned mx = umx(k1, o1);
                    k1 = umn(k1, o1);
                    k2 = umn(umn(k2, o2), mx);
                }
                int rloc = i * 16 + lg * 4 + qq;                  // 0..63
                if ((t & 1) == 0) {
                    if (l15 == 0) top2buf[wid][rloc] = make_uint2(k1, k2);
                } else if (l15 == 0) {
                    uint2 pe = top2buf[wid][rloc];
                    unsigned mx = umx(k1, pe.x);
                    k1 = umn(k1, pe.x);
                    k2 = umn(umn(k2, pe.y), mx);
                    float m1 = __uint_as_float(k1 & 0xFFFFFF80u) - 0.5f;  // <= true min
                    float m2 = __uint_as_float(k2 & 0xFFFFFF80u) - 0.5f;  // <= true 2nd
                    wsp[(size_t)(wr0 + rloc) * 64 + (c0 >> 7)] =
                        make_uint2(__float_as_uint(m1),
                                   (bf16_rd(m2) << 16) | (k1 & 0x7Fu));
                }
            }
        }
    }
}

// ---------- pass 2: candidate-column exact np re-eval + argmin + gather (proven) ----------
__global__ __launch_bounds__(256) void vq_pass2(
        const float* __restrict__ z, const float* __restrict__ e,
        const float* __restrict__ z2, const float* __restrict__ e2,
        const uint2* __restrict__ wsp, float* __restrict__ out) {
    __shared__ __align__(16) float zrow[4][ED];
    const int wid = threadIdx.x >> 6, lane = threadIdx.x & 63;
    const int r = blockIdx.x * 4 + wid;

    *reinterpret_cast<float4*>(&zrow[wid][lane * 4]) =
        *reinterpret_cast<const float4*>(z + (size_t)r * ED + lane * 4);
    __syncthreads();

    const float z2r = z2[r];
    uint2 p = wsp[(size_t)r * 64 + lane];                 // one 128-chunk per lane
    float m1 = __uint_as_float(p.x);
    int   i8 = (int)(p.y & 0xFFu);
    float m2 = __uint_as_float(p.y & 0xFFFF0000u);        // conservative (<= true m2)

    float rmn = m1;
#pragma unroll
    for (int off = 1; off < 64; off <<= 1) rmn = fminf(rmn, __shfl_xor(rmn, off));
    const float thr = rmn + DELTA;

    const bool cF = (m2 <= thr);
    const bool cS = (m1 <= thr) && !cF;
    unsigned long long bS = __ballot(cS);
    unsigned long long bF = __ballot(cF);

    float bd = 3.4e38f;
    int   bc = NE;

    // ---- single-column candidates: batch into lanes, one col per lane ----
    int myCol = -1;
    int cnt = 0;
    unsigned long long m = bS;
    while (true) {
        bool flush = (m == 0) || (cnt == 64);
        if (flush) {
            if (cnt > 0) {
                int ecol = (myCol >= 0) ? myCol : 0;
                const float* ec = e + (size_t)ecol * ED;
                float a0 = 0.f, a1 = 0.f, a2 = 0.f, a3 = 0.f;
#pragma unroll 8
                for (int t = 0; t < 64; ++t) {
                    float4 ev = *reinterpret_cast<const float4*>(ec + 4 * t);
                    float4 zv = *reinterpret_cast<const float4*>(&zrow[wid][4 * t]);
                    a0 = __fadd_rn(a0, __fmul_rn(zv.x, ev.x));
                    a1 = __fadd_rn(a1, __fmul_rn(zv.y, ev.y));
                    a2 = __fadd_rn(a2, __fmul_rn(zv.z, ev.z));
                    a3 = __fadd_rn(a3, __fmul_rn(zv.w, ev.w));
                }
                float s = __fadd_rn(__fadd_rn(a0, a1), __fadd_rn(a2, a3));
                float d = __fsub_rn(__fadd_rn(z2r, e2[ecol]), __fmul_rn(2.0f, s));
                if (myCol >= 0 && (d < bd || (d == bd && ecol < bc))) { bd = d; bc = ecol; }
                myCol = -1; cnt = 0;
            }
            if (m == 0) break;
        }
        int ch = __builtin_ctzll(m); m &= m - 1;
        int col = ch * 128 + __shfl(i8, ch);
        if (lane == cnt) myCol = col;
        ++cnt;
    }

    // ---- full-chunk candidates (rare; covers exact d'-ties automatically) ----
    m = bF;
    while (m) {
        int ch = __builtin_ctzll(m); m &= m - 1;
#pragma unroll
        for (int hh = 0; hh < 2; ++hh) {
            int col = ch * 128 + hh * 64 + lane;
            const float* ec = e + (size_t)col * ED;
            float a0 = 0.f, a1 = 0.f, a2 = 0.f, a3 = 0.f;
#pragma unroll 8
            for (int t = 0; t < 64; ++t) {
                float4 ev = *reinterpret_cast<const float4*>(ec + 4 * t);
                float4 zv = *reinterpret_cast<const float4*>(&zrow[wid][4 * t]);
                a0 = __fadd_rn(a0, __fmul_rn(zv.x, ev.x));
                a1 = __fadd_rn(a1, __fmul_rn(zv.y, ev.y));
                a2 = __fadd_rn(a2, __fmul_rn(zv.z, ev.z));
                a3 = __fadd_rn(a3, __fmul_rn(zv.w, ev.w));
            }
            float s = __fadd_rn(__fadd_rn(a0, a1), __fadd_rn(a2, a3));
            float d = __fsub_rn(__fadd_rn(z2r, e2[col]), __fmul_rn(2.0f, s));
            if (d < bd || (d == bd && col < bc)) { bd = d; bc = col; }
        }
    }

#pragma unroll
    for (int off = 1; off < 64; off <<= 1) {
        float od = __shfl_xor(bd, off);
        int   oc = __shfl_xor(bc, off);
        if (od < bd || (od == bd && oc < bc)) { bd = od; bc = oc; }
    }
    if (lane == 0) out[(size_t)BS * ED + r] = (float)bc;
    *reinterpret_cast<float4*>(out + (size_t)r * ED + lane * 4) =
        *reinterpret_cast<const float4*>(e + (size_t)bc * ED + lane * 4);
}

extern "C" void kernel_launch(void* const* d_in, const int* in_sizes, int n_in,
                              void* d_out, int out_size, void* d_ws, size_t ws_size,
                              hipStream_t stream) {
    const float* z = (const float*)d_in[0];
    const float* e = (const float*)d_in[1];
    float* out   = (float*)d_out;
    float* e2np  = (float*)d_ws;                     // 8192 f32
    float* z2np  = e2np + NE;                        // 32768 f32
    uint2* wsp   = (uint2*)(z2np + BS);              // 32768 x 64 x 8B = 16 MB
    short* eb    = (short*)(wsp + (size_t)BS * 64);  // 8192 x 256 bf16 = 4 MB

    hipLaunchKernelGGL(sq_np_kernel, dim3(NE / 32), dim3(256), 0, stream, e, e2np);
    hipLaunchKernelGGL(sq_np_kernel, dim3(BS / 32), dim3(256), 0, stream, z, z2np);
    hipLaunchKernelGGL(cvt_bf16_kernel, dim3(NE * ED / 8 / 256), dim3(256), 0, stream, e, eb);
    hipLaunchKernelGGL(vq_pass1, dim3((BS / 512) * 4), dim3(512), 0, stream,
                       z, (const char*)eb, e2np, wsp);
    hipLaunchKernelGGL(vq_pass2, dim3(BS / 4), dim3(256), 0, stream, z, e, z2np, e2np, wsp, out);
}

// Round 8
// 334.948 us; speedup vs baseline: 1.7662x; 1.4106x over previous
//
#include <hip/hip_runtime.h>

constexpr int NE = 8192;
constexpr int ED = 256;
constexpr int BS = 32768;
constexpr float DELTA = 4e-4f;   // >> 2*(bf16-MFMA err) + np-grid + key-quantization (~7.6e-6)

typedef short bf16x8 __attribute__((ext_vector_type(8)));
typedef float f32x4 __attribute__((ext_vector_type(4)));

#define GLOAD_LDS16(g, l) __builtin_amdgcn_global_load_lds( \
    (const __attribute__((address_space(1))) void*)(g),     \
    (__attribute__((address_space(3))) void*)(l), 16, 0, 0)

__device__ __forceinline__ short f2bf(float f) {            // RNE f32 -> bf16
    unsigned u = __float_as_uint(f);
    u = u + 0x7FFFu + ((u >> 16) & 1u);
    return (short)(u >> 16);
}
__device__ __forceinline__ unsigned bf16_rd(float x) {      // round toward -inf -> bf16 bits
    unsigned u = __float_as_uint(x);
    unsigned h = u >> 16;
    if ((u & 0x80000000u) && (u & 0xFFFFu)) ++h;
    return h;
}
__device__ __forceinline__ unsigned umn(unsigned a, unsigned b) { return a < b ? a : b; }
__device__ __forceinline__ unsigned umx(unsigned a, unsigned b) { return a > b ? a : b; }

// ---------- np-exact pairwise ||row||^2 (verified bit-exact vs np.sum in R2) ----------
// out5 (optional): +0.5 biased copy for pass1 keys.
__global__ void sq_np_kernel(const float* __restrict__ a, float* __restrict__ out,
                             float* __restrict__ out5) {
    int gtid = blockIdx.x * blockDim.x + threadIdx.x;
    int wave = gtid >> 6;
    int lane = threadIdx.x & 63;
    int sub  = lane & 7;
    int row  = wave * 8 + (lane >> 3);
    const float* p = a + (size_t)row * ED;
    float b0 = 0.f, b1 = 0.f;
#pragma unroll
    for (int t = 0; t < 16; ++t) { float v = p[8 * t + sub];       b0 = __fadd_rn(b0, __fmul_rn(v, v)); }
#pragma unroll
    for (int t = 0; t < 16; ++t) { float v = p[128 + 8 * t + sub]; b1 = __fadd_rn(b1, __fmul_rn(v, v)); }
    b0 = __fadd_rn(b0, __shfl_xor(b0, 1));
    b0 = __fadd_rn(b0, __shfl_xor(b0, 2));
    b0 = __fadd_rn(b0, __shfl_xor(b0, 4));
    b1 = __fadd_rn(b1, __shfl_xor(b1, 1));
    b1 = __fadd_rn(b1, __shfl_xor(b1, 2));
    b1 = __fadd_rn(b1, __shfl_xor(b1, 4));
    float tot = __fadd_rn(b0, b1);
    if (sub == 0) {
        out[row] = tot;
        if (out5) out5[row] = tot + 0.5f;
    }
}

// ---------- convert e (f32) -> eb (bf16), row-major, once ----------
__global__ void cvt_bf16_kernel(const float* __restrict__ a, short* __restrict__ o) {
    int i = blockIdx.x * blockDim.x + threadIdx.x;     // one per 8 elements
    const float4* p = reinterpret_cast<const float4*>(a + (size_t)i * 8);
    float4 v0 = p[0], v1 = p[1];
    bf16x8 h;
    h[0] = f2bf(v0.x); h[1] = f2bf(v0.y); h[2] = f2bf(v0.z); h[3] = f2bf(v0.w);
    h[4] = f2bf(v1.x); h[5] = f2bf(v1.y); h[6] = f2bf(v1.z); h[7] = f2bf(v1.w);
    *reinterpret_cast<bf16x8*>(o + (size_t)i * 8) = h;
}

// ---------- pass 1: swapped-operand MFMA (D = e·z^T), reg top-2 epilogue ----------
// 8 waves x 32 z-rows = 256 rows/block; col-quarter (2048 cols) = 32 tiles of 64.
// acc: col(lane&15) = z-row, row(lg*4+reg) = e-col -> argmin axis in registers.
__global__ __launch_bounds__(512, 4) void vq_pass1(
        const float* __restrict__ z, const char* __restrict__ eb,
        const float* __restrict__ e2p, uint2* __restrict__ wsp) {
    __shared__ __align__(16) char Bs[2][32768];      // e-tiles: 64 cols x 512 B (swizzled)

    const int tid  = threadIdx.x;
    const int wid  = tid >> 6, lane = tid & 63;
    const int l15  = lane & 15, lg = lane >> 4;
    const int kblk = blockIdx.x;
    const int rg   = (kblk & 7) | ((kblk >> 5) << 3);   // row-group: quarters share XCD
    const int q    = (kblk >> 3) & 3;
    const int brow = rg * 256;
    const int c0q  = q * 2048;
    const int wr0  = brow + wid * 32;
    const int swz  = (l15 & 7) << 4;

    // ---- prologue: stage tile 0 ----
#pragma unroll
    for (int it = 0; it < 4; ++it) {
        int slot = it * 512 + tid;                   // 0..2047 = 64 cols x 32 16B-units
        int c = slot >> 5, m = slot & 31;
        GLOAD_LDS16(eb + (size_t)(c0q + c) * 512 + ((m ^ (c & 7)) << 4),
                    &Bs[0][slot * 16]);
    }
    // ---- z rows -> registers (bf16), 32 rows/wave ----
    bf16x8 zreg[2][8];
#pragma unroll
    for (int j = 0; j < 2; ++j) {
        const float* zr = z + (size_t)(wr0 + j * 16 + l15) * ED + lg * 8;
#pragma unroll
        for (int t8 = 0; t8 < 8; ++t8) {
            float4 v0 = *reinterpret_cast<const float4*>(zr + t8 * 32);
            float4 v1 = *reinterpret_cast<const float4*>(zr + t8 * 32 + 4);
            bf16x8 h;
            h[0] = f2bf(v0.x); h[1] = f2bf(v0.y); h[2] = f2bf(v0.z); h[3] = f2bf(v0.w);
            h[4] = f2bf(v1.x); h[5] = f2bf(v1.y); h[6] = f2bf(v1.z); h[7] = f2bf(v1.w);
            zreg[j][t8] = h;
        }
    }

    unsigned rk1[2], rk2[2];
#pragma unroll 2
    for (int t = 0; t < 32; ++t) {
        const int buf = t & 1;
        __syncthreads();                 // drains vmcnt(0): tile t staged; prev reads done
        if (t < 31) {                    // prefetch next tile into other buffer
            const char* src = eb + (size_t)(c0q + (t + 1) * 64) * 512;
#pragma unroll
            for (int it = 0; it < 4; ++it) {
                int slot = it * 512 + tid;
                int c = slot >> 5, m = slot & 31;
                GLOAD_LDS16(src + (size_t)c * 512 + ((m ^ (c & 7)) << 4),
                            &Bs[buf ^ 1][slot * 16]);
            }
        }

        f32x4 acc[4][2];
#pragma unroll
        for (int i = 0; i < 4; ++i)
#pragma unroll
            for (int j = 0; j < 2; ++j) acc[i][j] = (f32x4){0.f, 0.f, 0.f, 0.f};

#pragma unroll
        for (int t8 = 0; t8 < 8; ++t8) {
            bf16x8 af[4];
#pragma unroll
            for (int i = 0; i < 4; ++i)
                af[i] = *reinterpret_cast<const bf16x8*>(
                    &Bs[buf][(i * 16 + l15) * 512 + (((t8 * 4 + lg) * 16) ^ swz)]);
#pragma unroll
            for (int i = 0; i < 4; ++i)
#pragma unroll
                for (int j = 0; j < 2; ++j)
                    acc[i][j] = __builtin_amdgcn_mfma_f32_16x16x32_bf16(
                        af[i], zreg[j][t8], acc[i][j], 0, 0, 0);
        }

        // ---- epilogue: in-register top-2 per z-row over this 64-col tile ----
        const int c0 = c0q + t * 64;
        const unsigned cb = (unsigned)((t & 1) * 64 + lg * 4);
#pragma unroll
        for (int j = 0; j < 2; ++j) {
            unsigned c1 = 0xFFFFFFFFu, c2 = 0xFFFFFFFFu;
#pragma unroll
            for (int i = 0; i < 4; ++i) {
                f32x4 e2v = *reinterpret_cast<const f32x4*>(e2p + c0 + i * 16 + lg * 4);
#pragma unroll
                for (int qp = 0; qp < 2; ++qp) {
                    float va = fmaf(-2.f, acc[i][j][qp * 2],     e2v[qp * 2]);
                    float vb = fmaf(-2.f, acc[i][j][qp * 2 + 1], e2v[qp * 2 + 1]);
                    unsigned ka = (__float_as_uint(va) & 0xFFFFFF80u) | (cb + i * 16 + qp * 2);
                    unsigned kb = (__float_as_uint(vb) & 0xFFFFFF80u) | (cb + i * 16 + qp * 2 + 1);
                    unsigned lo = umn(ka, kb), hi = umx(ka, kb);
                    unsigned mx = umx(c1, lo);
                    c1 = umn(c1, lo);
                    c2 = umn(umn(c2, hi), mx);
                }
            }
#pragma unroll
            for (int off = 16; off < 64; off <<= 1) {    // merge across lg groups
                unsigned o1 = (unsigned)__shfl_xor((int)c1, off);
                unsigned o2 = (unsigned)__shfl_xor((int)c2, off);
                unsigned mx = umx(c1, o1);
                c1 = umn(c1, o1);
                c2 = umn(umn(c2, o2), mx);
            }
            if ((t & 1) == 0) {
                rk1[j] = c1; rk2[j] = c2;
            } else {
                unsigned M1 = umn(rk1[j], c1);
                unsigned M2 = umn(umn(rk2[j], c2), umx(rk1[j], c1));
                if (lg == 0) {
                    float m1f = __uint_as_float(M1 & 0xFFFFFF80u) - 0.5f;  // <= true min
                    float m2f = __uint_as_float(M2 & 0xFFFFFF80u) - 0.5f;  // <= true 2nd
                    wsp[(size_t)(wr0 + j * 16 + l15) * 64 + (q * 16 + (t >> 1))] =
                        make_uint2(__float_as_uint(m1f),
                                   (bf16_rd(m2f) << 16) | (M1 & 0x7Fu));
                }
            }
        }
    }
}

// ---------- pass 2: candidate-column exact np re-eval + argmin + gather (proven) ----------
__global__ __launch_bounds__(256) void vq_pass2(
        const float* __restrict__ z, const float* __restrict__ e,
        const float* __restrict__ z2, const float* __restrict__ e2,
        const uint2* __restrict__ wsp, float* __restrict__ out) {
    __shared__ __align__(16) float zrow[4][ED];
    const int wid = threadIdx.x >> 6, lane = threadIdx.x & 63;
    const int r = blockIdx.x * 4 + wid;

    *reinterpret_cast<float4*>(&zrow[wid][lane * 4]) =
        *reinterpret_cast<const float4*>(z + (size_t)r * ED + lane * 4);
    __syncthreads();

    const float z2r = z2[r];
    uint2 p = wsp[(size_t)r * 64 + lane];                 // one 128-chunk per lane
    float m1 = __uint_as_float(p.x);
    int   i8 = (int)(p.y & 0xFFu);
    float m2 = __uint_as_float(p.y & 0xFFFF0000u);        // conservative (<= true m2)

    float rmn = m1;
#pragma unroll
    for (int off = 1; off < 64; off <<= 1) rmn = fminf(rmn, __shfl_xor(rmn, off));
    const float thr = rmn + DELTA;

    const bool cF = (m2 <= thr);
    const bool cS = (m1 <= thr) && !cF;
    unsigned long long bS = __ballot(cS);
    unsigned long long bF = __ballot(cF);

    float bd = 3.4e38f;
    int   bc = NE;

    // ---- single-column candidates: batch into lanes, one col per lane ----
    int myCol = -1;
    int cnt = 0;
    unsigned long long m = bS;
    while (true) {
        bool flush = (m == 0) || (cnt == 64);
        if (flush) {
            if (cnt > 0) {
                int ecol = (myCol >= 0) ? myCol : 0;
                const float* ec = e + (size_t)ecol * ED;
                float a0 = 0.f, a1 = 0.f, a2 = 0.f, a3 = 0.f;
#pragma unroll 8
                for (int t = 0; t < 64; ++t) {
                    float4 ev = *reinterpret_cast<const float4*>(ec + 4 * t);
                    float4 zv = *reinterpret_cast<const float4*>(&zrow[wid][4 * t]);
                    a0 = __fadd_rn(a0, __fmul_rn(zv.x, ev.x));
                    a1 = __fadd_rn(a1, __fmul_rn(zv.y, ev.y));
                    a2 = __fadd_rn(a2, __fmul_rn(zv.z, ev.z));
                    a3 = __fadd_rn(a3, __fmul_rn(zv.w, ev.w));
                }
                float s = __fadd_rn(__fadd_rn(a0, a1), __fadd_rn(a2, a3));
                float d = __fsub_rn(__fadd_rn(z2r, e2[ecol]), __fmul_rn(2.0f, s));
                if (myCol >= 0 && (d < bd || (d == bd && ecol < bc))) { bd = d; bc = ecol; }
                myCol = -1; cnt = 0;
            }
            if (m == 0) break;
        }
        int ch = __builtin_ctzll(m); m &= m - 1;
        int col = ch * 128 + __shfl(i8, ch);
        if (lane == cnt) myCol = col;
        ++cnt;
    }

    // ---- full-chunk candidates (rare; covers exact d'-ties automatically) ----
    m = bF;
    while (m) {
        int ch = __builtin_ctzll(m); m &= m - 1;
#pragma unroll
        for (int hh = 0; hh < 2; ++hh) {
            int col = ch * 128 + hh * 64 + lane;
            const float* ec = e + (size_t)col * ED;
            float a0 = 0.f, a1 = 0.f, a2 = 0.f, a3 = 0.f;
#pragma unroll 8
            for (int t = 0; t < 64; ++t) {
                float4 ev = *reinterpret_cast<const float4*>(ec + 4 * t);
                float4 zv = *reinterpret_cast<const float4*>(&zrow[wid][4 * t]);
                a0 = __fadd_rn(a0, __fmul_rn(zv.x, ev.x));
                a1 = __fadd_rn(a1, __fmul_rn(zv.y, ev.y));
                a2 = __fadd_rn(a2, __fmul_rn(zv.z, ev.z));
                a3 = __fadd_rn(a3, __fmul_rn(zv.w, ev.w));
            }
            float s = __fadd_rn(__fadd_rn(a0, a1), __fadd_rn(a2, a3));
            float d = __fsub_rn(__fadd_rn(z2r, e2[col]), __fmul_rn(2.0f, s));
            if (d < bd || (d == bd && col < bc)) { bd = d; bc = col; }
        }
    }

#pragma unroll
    for (int off = 1; off < 64; off <<= 1) {
        float od = __shfl_xor(bd, off);
        int   oc = __shfl_xor(bc, off);
        if (od < bd || (od == bd && oc < bc)) { bd = od; bc = oc; }
    }
    if (lane == 0) out[(size_t)BS * ED + r] = (float)bc;
    *reinterpret_cast<float4*>(out + (size_t)r * ED + lane * 4) =
        *reinterpret_cast<const float4*>(e + (size_t)bc * ED + lane * 4);
}

extern "C" void kernel_launch(void* const* d_in, const int* in_sizes, int n_in,
                              void* d_out, int out_size, void* d_ws, size_t ws_size,
                              hipStream_t stream) {
    const float* z = (const float*)d_in[0];
    const float* e = (const float*)d_in[1];
    float* out   = (float*)d_out;
    float* e2np  = (float*)d_ws;                     // 8192 f32 (exact, for pass2)
    float* e2p5  = e2np + NE;                        // 8192 f32 (+0.5, for pass1 keys)
    float* z2np  = e2p5 + NE;                        // 32768 f32
    uint2* wsp   = (uint2*)(z2np + BS);              // 32768 x 64 x 8B = 16 MB
    short* eb    = (short*)(wsp + (size_t)BS * 64);  // 8192 x 256 bf16 = 4 MB

    hipLaunchKernelGGL(sq_np_kernel, dim3(NE / 32), dim3(256), 0, stream, e, e2np, e2p5);
    hipLaunchKernelGGL(sq_np_kernel, dim3(BS / 32), dim3(256), 0, stream, z, z2np, (float*)nullptr);
    hipLaunchKernelGGL(cvt_bf16_kernel, dim3(NE * ED / 8 / 256), dim3(256), 0, stream, e, eb);
    hipLaunchKernelGGL(vq_pass1, dim3(512), dim3(512), 0, stream,
                       z, (const char*)eb, e2p5, wsp);
    hipLaunchKernelGGL(vq_pass2, dim3(BS / 4), dim3(256), 0, stream, z, e, z2np, e2np, wsp, out);
}